// Round 14
// baseline (46.892 us; speedup 1.0000x reference)
//
#include <hip/hip_runtime.h>
#include <math.h>

#define D 128
#define DEG 64           // per-node slot capacity (mean degree 32)
#define BK 512           // dst buckets per direction (16 nodes/bucket = 1 loss block)
#define CH 128           // edge chunks per direction (2048 edges/chunk)
#define CAP 24           // slots per (bucket,chunk) cell; mean 4, P(any overflow)~1e-10

typedef __attribute__((ext_vector_type(8))) short bf8;
typedef __attribute__((ext_vector_type(4))) float f4;

__device__ __forceinline__ unsigned hash_u32(unsigned x){
  x ^= x >> 16; x *= 0x7feb352du; x ^= x >> 15; x *= 0x846ca68bu; x ^= x >> 16;
  return x;
}
__device__ __forceinline__ unsigned f2bfbits(float f){
  unsigned u = __float_as_uint(f);
  return (u + 0x7fffu + ((u >> 16) & 1u)) >> 16;   // RNE bf16
}
__device__ __forceinline__ float bflo(unsigned u){ return __uint_as_float(u << 16); }
__device__ __forceinline__ float bfhi(unsigned u){ return __uint_as_float(u & 0xffff0000u); }
__device__ __forceinline__ uint4 pack8(float4 v0, float4 v1){
  uint4 o;
  o.x = f2bfbits(v0.x) | (f2bfbits(v0.y) << 16);
  o.y = f2bfbits(v0.z) | (f2bfbits(v0.w) << 16);
  o.z = f2bfbits(v1.x) | (f2bfbits(v1.y) << 16);
  o.w = f2bfbits(v1.z) | (f2bfbits(v1.w) << 16);
  return o;
}
// XCD-aware type partition (perf heuristic; bijective, correctness-neutral).
__device__ __forceinline__ int xcd_remap(int bid, int jobs_per_type){
  if (jobs_per_type & 3) return bid;
  const int xcd = bid & 7, slot = bid >> 3;
  const int q = jobs_per_type >> 2;
  return (xcd >> 2) * jobs_per_type + (xcd & 3) * q + slot;
}

struct LinS { alignas(16) ushort Ws[64 * 128]; alignas(16) ushort As[4][16 * 128]; }; // 32KB
struct BinS { int hist[BK]; int ex[BK]; int cur[BK]; int wtot[4]; unsigned buf[2048]; }; // ~14.3KB
union SharedU { LinS lin; BinS bin; };

// ---- K1: linear (256 blk) || fixed-slot bin (256 blk) || 1 out-zero block -
// UNCHANGED from r13 (control).
__global__ __launch_bounds__(256)
void linear_bin(const float* __restrict__ xa, const float* __restrict__ xb,
                const float* __restrict__ Wa, const float* __restrict__ Wb,
                const float* __restrict__ ba, const float* __restrict__ bb,
                ushort* __restrict__ x16a, ushort* __restrict__ x16b,
                ushort* __restrict__ oa, ushort* __restrict__ ob,
                const int* __restrict__ e_ba, const int* __restrict__ e_ab,
                unsigned* __restrict__ scratch, unsigned* __restrict__ ccnt,
                float* __restrict__ out0, int E, int N){
  const int LB = 2 * (N >> 6);                   // 256 linear blocks (LB%8==0)
  __shared__ SharedU sh;

  if ((int)blockIdx.x < LB){
    // ---------------- ctx0 = bf16(x @ W^T + b) via MFMA (unchanged) -------
    const int nb64 = N >> 6;
    const int jid = xcd_remap((int)blockIdx.x, nb64);
    const int type = jid >= nb64;
    const int r0 = (jid - (type ? nb64 : 0)) << 6;
    const float* __restrict__ x = type ? xb : xa;
    const float* __restrict__ W = type ? Wb : Wa;
    const float* __restrict__ bias = type ? bb : ba;
    ushort* __restrict__ x16 = type ? x16b : x16a;
    ushort* __restrict__ out = type ? ob : oa;
    const int t = threadIdx.x, w = t >> 6, l = t & 63;

    #define STAGE_W(H)                                                        \
    {                                                                         \
      _Pragma("unroll")                                                       \
      for (int i = 0; i < 4; i++){                                            \
        const int cid = i * 256 + t;                                          \
        const int col = cid >> 4, kq = cid & 15;                              \
        const int gcol = (H) * 64 + col;                                      \
        const float4 v0 = *(const float4*)(W + (gcol << 7) + (kq << 3));      \
        const float4 v1 = *(const float4*)(W + (gcol << 7) + (kq << 3) + 4);  \
        *(uint4*)&sh.lin.Ws[(col << 7) + ((kq ^ (col & 7)) << 3)] = pack8(v0, v1); \
      }                                                                       \
    }

    #pragma unroll
    for (int i = 0; i < 4; i++){
      const int cid = i * 64 + l;
      const int row = cid >> 4, kq = cid & 15;
      const size_t gr = (size_t)(r0 + w * 16 + row);
      const float4 v0 = *(const float4*)(x + (gr << 7) + (kq << 3));
      const float4 v1 = *(const float4*)(x + (gr << 7) + (kq << 3) + 4);
      const uint4 o = pack8(v0, v1);
      *(uint4*)&sh.lin.As[w][(row << 7) + ((kq ^ (row & 7)) << 3)] = o;
      *(uint4*)(x16 + (gr << 7) + (kq << 3)) = o;  // 1KB/instr coalesced
    }
    STAGE_W(0)
    __syncthreads();

    const int rloc = l & 15, kg = l >> 4;
    bf8 af[4];
    #pragma unroll
    for (int ks = 0; ks < 4; ks++){
      const int kq = ks * 4 + kg;
      af[ks] = *(const bf8*)&sh.lin.As[w][(rloc << 7) + ((kq ^ (rloc & 7)) << 3)];
    }
    #pragma unroll
    for (int h = 0; h < 2; h++){
      if (h == 1){
        __syncthreads();
        STAGE_W(1)
        __syncthreads();
      }
      #pragma unroll
      for (int c2 = 0; c2 < 4; c2++){
        const int ct = h * 4 + c2;
        f4 acc = {0.f, 0.f, 0.f, 0.f};
        const int col = ct * 16 + rloc;
        const int lcol = c2 * 16 + rloc;          // (col&7)==(lcol&7)
        #pragma unroll
        for (int ks = 0; ks < 4; ks++){
          const int kq = ks * 4 + kg;
          const bf8 bfr = *(const bf8*)&sh.lin.Ws[(lcol << 7) + ((kq ^ (lcol & 7)) << 3)];
          acc = __builtin_amdgcn_mfma_f32_16x16x32_bf16(af[ks], bfr, acc, 0, 0, 0);
        }
        const float bv = bias[col];
        #pragma unroll
        for (int r = 0; r < 4; r++){
          const int row = r0 + w * 16 + kg * 4 + r;
          out[((size_t)row << 7) + col] = (ushort)f2bfbits(acc[r] + bv);
        }
      }
    }
    #undef STAGE_W
  } else if ((int)blockIdx.x < LB + 2 * CH){
    // -------- fixed-slot binning: block owns (dir, chunk of 2048) ----------
    const int sbid = (int)blockIdx.x - LB;       // 0..255
    const int d = sbid >> 7, chunk = sbid & 127;
    const int* __restrict__ e = d ? e_ab : e_ba;
    const int t = threadIdx.x;
    sh.bin.hist[t] = 0; sh.bin.hist[t + 256] = 0;
    __syncthreads();

    int ds[8], ss[8];
    const int base = chunk * 2048;
    #pragma unroll
    for (int k = 0; k < 8; k++){
      const int i = base + k * 256 + t;
      const bool ok = i < E;
      ds[k] = ok ? e[E + i] : -1;
      ss[k] = ok ? e[i] : 0;
      if (ok) atomicAdd(&sh.bin.hist[ds[k] >> 4], 1);   // LDS atomic, 512 bins
    }
    __syncthreads();
    // 512-bin scan: pair-per-thread, wave shfl scans + cross-wave offsets
    const int h0 = sh.bin.hist[2 * t], h1 = sh.bin.hist[2 * t + 1];
    const int pv = h0 + h1;
    {
      int v = pv;
      #pragma unroll
      for (int off = 1; off < 64; off <<= 1){
        const int u = __shfl_up(v, off, 64);
        if ((t & 63) >= off) v += u;
      }
      if ((t & 63) == 63) sh.bin.wtot[t >> 6] = v;
      sh.bin.ex[2 * t] = v;                       // temp: inclusive pair scan
    }
    __syncthreads();
    {
      const int wv = t >> 6;
      int add = 0;
      if (wv > 0) add += sh.bin.wtot[0];
      if (wv > 1) add += sh.bin.wtot[1];
      if (wv > 2) add += sh.bin.wtot[2];
      const int pex = sh.bin.ex[2 * t] + add - pv;   // exclusive start of pair
      sh.bin.ex[2 * t] = pex;      sh.bin.ex[2 * t + 1] = pex + h0;
      sh.bin.cur[2 * t] = pex;     sh.bin.cur[2 * t + 1] = pex + h0;
    }
    __syncthreads();
    #pragma unroll
    for (int k = 0; k < 8; k++){
      if (ds[k] >= 0){
        const int p = atomicAdd(&sh.bin.cur[ds[k] >> 4], 1);   // LDS atomic
        sh.bin.buf[p] = (unsigned)ss[k] | ((unsigned)ds[k] << 13);
      }
    }
    __syncthreads();
    int nv = E - base; nv = nv < 0 ? 0 : (nv > 2048 ? 2048 : nv);
    ccnt[((size_t)d * BK + 2 * t) * CH + chunk]     = (unsigned)min(h0, CAP);
    ccnt[((size_t)d * BK + 2 * t + 1) * CH + chunk] = (unsigned)min(h1, CAP);
    for (int s = t; s < nv; s += 256){
      const unsigned v = sh.bin.buf[s];
      const int bkt = (int)(v >> 17);            // dst>>4
      const int gp = s - sh.bin.ex[bkt];
      if (gp < CAP) scratch[((size_t)(d * BK + bkt) * CH + chunk) * CAP + gp] = v;
    }
  } else {
    if (threadIdx.x == 0) *out0 = 0.0f;
  }
}

// ---- K2: 1024 blk x 256 thr x 16 rows. This round: ENTRY-PREFETCH — the
// first two phase-2 tile-sets (x16 row fragments) depend only on the hash,
// so they are issued at kernel entry and their latency hides under phases
// 0-1. All arithmetic, tile order, and LSE order bit-identical to r13. ------
__global__ __launch_bounds__(256)
void loss_fused(const ushort* __restrict__ xa, const ushort* __restrict__ xb,
                const ushort* __restrict__ ctx0a, const ushort* __restrict__ ctx0b,
                const unsigned* __restrict__ scratch, const unsigned* __restrict__ ccnt,
                float* __restrict__ out, int n){
  const int nb = n >> 4;                          // 512 jobs per type (16 rows)
  const int jid = xcd_remap((int)blockIdx.x, nb); // XCDs 0-3: type 0, 4-7: type 1
  const int type = jid >= nb;
  const int j16 = jid - (type ? nb : 0);
  const int r0 = j16 << 4;                        // within-type row base
  const ushort* __restrict__ x    = type ? xb : xa;
  const ushort* __restrict__ feat = type ? ctx0a : ctx0b;  // src-side features
  const int t = threadIdx.x, w = t >> 6, l = t & 63;
  const int sg = l >> 4, q = l & 15;
  const int nloc = l & 15, kg = l >> 4;

  __shared__ alignas(16) ushort A[16 * 128];      // 4KB
  __shared__ float lpos[16];
  __shared__ float2 part[4][16];
  __shared__ int list[16 * DEG];                  // 4KB
  __shared__ int lcnt[16];
  __shared__ unsigned cc[CH];

  const unsigned h = hash_u32((unsigned)jid * 2654435761u + 0x9E3779B9u);
  const unsigned bo = h & 8191u;
  const unsigned aa = (((h >> 13) & 4095u) << 1) | 1u;

  // ---- entry-prefetch: tile-sets for tiles w and w+4 (independent of A) ---
  int colidA, gA; bool negA; bf8 b0A, b1A, b2A, b3A;
  int colidB, gB; bool negB; bf8 b0B, b1B, b2B, b3B;

  #define LOADSET(S, TILE)                                                     \
  {                                                                            \
    colid##S = (TILE) * 16 + nloc;                                             \
    neg##S = colid##S >= 16;                                                   \
    const int jn_ = colid##S - 16;                                             \
    g##S = neg##S ? (int)((aa * (unsigned)jn_ + bo) & 8191u) : (r0 + colid##S); \
    const ushort* __restrict__ xr_ = x + ((size_t)g##S << 7) + kg * 8;         \
    b0##S = *(const bf8*)(xr_);                                                \
    b1##S = *(const bf8*)(xr_ + 32);                                           \
    b2##S = *(const bf8*)(xr_ + 64);                                           \
    b3##S = *(const bf8*)(xr_ + 96);                                           \
  }

  LOADSET(A, w)
  LOADSET(B, w + 4)

  if (t < 16) lcnt[t] = 0;
  const size_t cellbase = (size_t)(type * BK + j16) * CH;  // bucket == j16
  if (t < CH) cc[t] = ccnt[cellbase + t];
  __syncthreads();

  { // phase 0: vec4 scan of OWN bucket only (1x amp, 12KB contiguous)
    for (int i4 = t * 4; i4 < CH * CAP; i4 += 256 * 4){    // 3 iters/thread
      const uint4 v4 = *(const uint4*)(scratch + cellbase * CAP + i4);
      const int cell = i4 / CAP;
      const int s0 = i4 - cell * CAP;
      const int cn = (int)cc[cell];
      #pragma unroll
      for (int j = 0; j < 4; j++){
        if (s0 + j < cn){
          const unsigned v = (&v4.x)[j];
          const int dl = (int)((v >> 13) & 8191u) - r0;    // in [0,16) by construction
          const int p = atomicAdd(&lcnt[dl], 1);
          if (p < DEG) list[dl * DEG + p] = (int)(v & 8191u);
        }
      }
    }
  }
  __syncthreads();

  { // phase 1: gather-mean, row = w*4+sg; 8 loads batched into regs (MLP)
    const int row = w * 4 + sg;
    const int c = min(lcnt[row], DEG);
    const int lb2 = row * DEG;
    int sl0 = list[lb2 + q];
    int sl1 = list[lb2 + 16 + q];
    int sl2 = list[lb2 + 32 + q];
    int sl3 = list[lb2 + 48 + q];

    float a0=0.f,a1=0.f,a2=0.f,a3=0.f,a4=0.f,a5=0.f,a6=0.f,a7=0.f;
    const int lbase = l & 48;
    #define GMEAN_HALF(SL, J, HB)                                              \
    {                                                                          \
      uint4 vv[8]; float wt[8];                                                \
      _Pragma("unroll")                                                        \
      for (int j = 0; j < 8; j++){                                             \
        const int i = (HB) * 8 + j;                                            \
        const int raw = __shfl((SL), lbase | i, 64);                           \
        const bool ok = (J)*16 + i < c;                                        \
        const int src = ok ? raw : 0;                                          \
        wt[j] = ok ? 1.0f : 0.0f;                                              \
        vv[j] = *(const uint4*)(feat + ((size_t)src << 7) + (q << 3));         \
      }                                                                        \
      _Pragma("unroll")                                                        \
      for (int j = 0; j < 8; j++){                                             \
        a0 += wt[j]*bflo(vv[j].x); a1 += wt[j]*bfhi(vv[j].x);                  \
        a2 += wt[j]*bflo(vv[j].y); a3 += wt[j]*bfhi(vv[j].y);                  \
        a4 += wt[j]*bflo(vv[j].z); a5 += wt[j]*bfhi(vv[j].z);                  \
        a6 += wt[j]*bflo(vv[j].w); a7 += wt[j]*bfhi(vv[j].w);                  \
      }                                                                        \
    }
    if (c >  0){ GMEAN_HALF(sl0, 0, 0) GMEAN_HALF(sl0, 0, 1) }
    if (c > 16){ GMEAN_HALF(sl1, 1, 0) GMEAN_HALF(sl1, 1, 1) }
    if (c > 32){ GMEAN_HALF(sl2, 2, 0) GMEAN_HALF(sl2, 2, 1) }
    if (c > 48){ GMEAN_HALF(sl3, 3, 0) GMEAN_HALF(sl3, 3, 1) }
    #undef GMEAN_HALF

    const float inv = 1.0f / (float)(c > 1 ? c : 1);
    uint4 o;
    o.x = f2bfbits(a0*inv) | (f2bfbits(a1*inv) << 16);
    o.y = f2bfbits(a2*inv) | (f2bfbits(a3*inv) << 16);
    o.z = f2bfbits(a4*inv) | (f2bfbits(a5*inv) << 16);
    o.w = f2bfbits(a6*inv) | (f2bfbits(a7*inv) << 16);
    *(uint4*)&A[(row << 7) + ((q ^ (row & 7)) << 3)] = o;
  }
  __syncthreads();

  // phase 2: 2-set software pipeline over tiles {w, w+4, w+8, w+12,
  // [16 if w==0]} — first two sets already in registers. LSE order = r13.
  bf8 af[4];
  #pragma unroll
  for (int ks = 0; ks < 4; ks++){
    const int kq = ks * 4 + kg;
    af[ks] = *(const bf8*)&A[(nloc << 7) + ((kq ^ (nloc & 7)) << 3)];
  }

  float M0=-1e30f, M1=-1e30f, M2=-1e30f, M3=-1e30f;
  float S0=0.f, S1=0.f, S2=0.f, S3=0.f;

  #define COMPUTESET(S)                                                        \
  {                                                                            \
    f4 acc = {0.f, 0.f, 0.f, 0.f};                                             \
    acc = __builtin_amdgcn_mfma_f32_16x16x32_bf16(af[0], b0##S, acc, 0, 0, 0); \
    acc = __builtin_amdgcn_mfma_f32_16x16x32_bf16(af[1], b1##S, acc, 0, 0, 0); \
    acc = __builtin_amdgcn_mfma_f32_16x16x32_bf16(af[2], b2##S, acc, 0, 0, 0); \
    acc = __builtin_amdgcn_mfma_f32_16x16x32_bf16(af[3], b3##S, acc, 0, 0, 0); \
    const int jn_ = colid##S - 16;                                             \
    _Pragma("unroll")                                                          \
    for (int r = 0; r < 4; r++){                                               \
      const int row_ = kg * 4 + r;                                             \
      const bool valid = neg##S ? (jn_ < 255 && g##S != r0 + row_)             \
                                : (colid##S == row_);                          \
      const float v = acc[r] * 10.0f;                                          \
      if (!neg##S && colid##S == row_) lpos[row_] = v;                         \
      float* Mp; float* Sp;                                                    \
      if (r == 0){ Mp = &M0; Sp = &S0; } else if (r == 1){ Mp = &M1; Sp = &S1; } \
      else if (r == 2){ Mp = &M2; Sp = &S2; } else { Mp = &M3; Sp = &S3; }     \
      if (valid){                                                              \
        const float Mn = fmaxf(*Mp, v);                                        \
        *Sp = *Sp * __expf(*Mp - Mn) + __expf(v - Mn);                         \
        *Mp = Mn;                                                              \
      }                                                                        \
    }                                                                          \
  }

  COMPUTESET(A)                  // tile w
  LOADSET(A, w + 8)
  COMPUTESET(B)                  // tile w+4
  LOADSET(B, w + 12)
  COMPUTESET(A)                  // tile w+8
  if (w == 0){ LOADSET(A, 16) }
  COMPUTESET(B)                  // tile w+12
  if (w == 0){ COMPUTESET(A) }   // tile 16 (negatives 240..254)
  #undef LOADSET
  #undef COMPUTESET

  #define MERGE_LANES(MV, SV)                          \
  {                                                    \
    _Pragma("unroll")                                  \
    for (int o = 1; o < 16; o <<= 1){                  \
      const float Mo = __shfl_xor((MV), o);            \
      const float So = __shfl_xor((SV), o);            \
      const float Mn = fmaxf((MV), Mo);                \
      (SV) = (SV) * __expf((MV) - Mn) + So * __expf(Mo - Mn); \
      (MV) = Mn;                                       \
    }                                                  \
  }
  MERGE_LANES(M0, S0) MERGE_LANES(M1, S1) MERGE_LANES(M2, S2) MERGE_LANES(M3, S3)
  #undef MERGE_LANES

  if (nloc == 0){
    part[w][kg * 4 + 0] = make_float2(M0, S0);
    part[w][kg * 4 + 1] = make_float2(M1, S1);
    part[w][kg * 4 + 2] = make_float2(M2, S2);
    part[w][kg * 4 + 3] = make_float2(M3, S3);
  }
  __syncthreads();

  if (w == 0 && l < 16){
    const int row = l;
    float Mm = -1e30f, Ss = 0.f;
    #pragma unroll
    for (int j = 0; j < 4; j++){
      const float2 ps = part[j][row];
      const float Mn = fmaxf(Mm, ps.x);
      Ss = Ss * __expf(Mm - Mn) + ps.y * __expf(ps.x - Mn);
      Mm = Mn;
    }
    float term = Mm + __logf(Ss) - lpos[row];
    #pragma unroll
    for (int o = 8; o >= 1; o >>= 1) term += __shfl_xor(term, o);
    if (l == 0) atomicAdd(out, term / (logf(256.0f) * (float)(2 * n)));
  }
}

extern "C" void kernel_launch(void* const* d_in, const int* in_sizes, int n_in,
                              void* d_out, int out_size, void* d_ws, size_t ws_size,
                              hipStream_t stream) {
  const float* x_a = (const float*)d_in[0];
  const float* x_b = (const float*)d_in[1];
  const float* W_a = (const float*)d_in[2];
  const float* b_a = (const float*)d_in[3];
  const float* W_b = (const float*)d_in[4];
  const float* b_b = (const float*)d_in[5];
  const int*   e_ab = (const int*)d_in[6];   // [2,E]: [0]=src(a), [1]=dst(b)
  const int*   e_ba = (const int*)d_in[7];   // [0]=src(b), [1]=dst(a)
  const int E = in_sizes[6] / 2;
  const int N = in_sizes[0] / D;             // 8192

  char* p = (char*)d_ws;
  ushort* xa16    = (ushort*)p;   p += (size_t)N * D * 2;
  ushort* xb16    = (ushort*)p;   p += (size_t)N * D * 2;
  ushort* ctx0a   = (ushort*)p;   p += (size_t)N * D * 2;
  ushort* ctx0b   = (ushort*)p;   p += (size_t)N * D * 2;
  unsigned* scratch = (unsigned*)p; p += (size_t)2 * BK * CH * CAP * 4;  // 12.6MB
  unsigned* ccnt  = (unsigned*)p; p += (size_t)2 * BK * CH * 4;          // 512KB

  linear_bin<<<2 * (N / 64) + 2 * CH + 1, 256, 0, stream>>>(
      x_a, x_b, W_a, W_b, b_a, b_b, xa16, xb16, ctx0a, ctx0b,
      e_ba, e_ab, scratch, ccnt, (float*)d_out, E, N);

  loss_fused<<<2 * (N / 16), 256, 0, stream>>>(
      xa16, xb16, ctx0a, ctx0b, scratch, ccnt, (float*)d_out, N);
}

// Round 15
// 42.467 us; speedup vs baseline: 1.1042x; 1.1042x over previous
//
#include <hip/hip_runtime.h>
#include <math.h>

#define D 128
#define DEG 64           // per-node slot capacity (mean degree 32)
#define BK 512           // dst buckets per direction (16 nodes/bucket = 1 loss block)
#define CH 128           // edge chunks per direction (2048 edges/chunk)
#define CAP 24           // slots per (bucket,chunk) cell; mean 4, P(any overflow)~1e-10

typedef __attribute__((ext_vector_type(8))) short bf8;
typedef __attribute__((ext_vector_type(4))) float f4;

__device__ __forceinline__ unsigned hash_u32(unsigned x){
  x ^= x >> 16; x *= 0x7feb352du; x ^= x >> 15; x *= 0x846ca68bu; x ^= x >> 16;
  return x;
}
__device__ __forceinline__ unsigned f2bfbits(float f){
  unsigned u = __float_as_uint(f);
  return (u + 0x7fffu + ((u >> 16) & 1u)) >> 16;   // RNE bf16
}
__device__ __forceinline__ float bflo(unsigned u){ return __uint_as_float(u << 16); }
__device__ __forceinline__ float bfhi(unsigned u){ return __uint_as_float(u & 0xffff0000u); }
__device__ __forceinline__ uint4 pack8(float4 v0, float4 v1){
  uint4 o;
  o.x = f2bfbits(v0.x) | (f2bfbits(v0.y) << 16);
  o.y = f2bfbits(v0.z) | (f2bfbits(v0.w) << 16);
  o.z = f2bfbits(v1.x) | (f2bfbits(v1.y) << 16);
  o.w = f2bfbits(v1.z) | (f2bfbits(v1.w) << 16);
  return o;
}
// XCD-aware type partition (perf heuristic; bijective, correctness-neutral).
__device__ __forceinline__ int xcd_remap(int bid, int jobs_per_type){
  if (jobs_per_type & 3) return bid;
  const int xcd = bid & 7, slot = bid >> 3;
  const int q = jobs_per_type >> 2;
  return (xcd >> 2) * jobs_per_type + (xcd & 3) * q + slot;
}

struct LinS { alignas(16) ushort Ws[64 * 128]; alignas(16) ushort As[4][16 * 128]; }; // 32KB
struct BinS { int hist[BK]; int ex[BK]; int cur[BK]; int wtot[4]; unsigned buf[2048]; }; // ~14.3KB
union SharedU { LinS lin; BinS bin; };

// ---- K1: linear (256 blk) || fixed-slot bin (256 blk) || 1 out-zero block -
__global__ __launch_bounds__(256)
void linear_bin(const float* __restrict__ xa, const float* __restrict__ xb,
                const float* __restrict__ Wa, const float* __restrict__ Wb,
                const float* __restrict__ ba, const float* __restrict__ bb,
                ushort* __restrict__ x16a, ushort* __restrict__ x16b,
                ushort* __restrict__ oa, ushort* __restrict__ ob,
                const int* __restrict__ e_ba, const int* __restrict__ e_ab,
                unsigned* __restrict__ scratch, unsigned* __restrict__ ccnt,
                float* __restrict__ out0, int E, int N){
  const int LB = 2 * (N >> 6);                   // 256 linear blocks (LB%8==0)
  __shared__ SharedU sh;

  if ((int)blockIdx.x < LB){
    // ---------------- ctx0 = bf16(x @ W^T + b) via MFMA -------------------
    const int nb64 = N >> 6;
    const int jid = xcd_remap((int)blockIdx.x, nb64);
    const int type = jid >= nb64;
    const int r0 = (jid - (type ? nb64 : 0)) << 6;
    const float* __restrict__ x = type ? xb : xa;
    const float* __restrict__ W = type ? Wb : Wa;
    const float* __restrict__ bias = type ? bb : ba;
    ushort* __restrict__ x16 = type ? x16b : x16a;
    ushort* __restrict__ out = type ? ob : oa;
    const int t = threadIdx.x, w = t >> 6, l = t & 63;

    #define STAGE_W(H)                                                        \
    {                                                                         \
      _Pragma("unroll")                                                       \
      for (int i = 0; i < 4; i++){                                            \
        const int cid = i * 256 + t;                                          \
        const int col = cid >> 4, kq = cid & 15;                              \
        const int gcol = (H) * 64 + col;                                      \
        const float4 v0 = *(const float4*)(W + (gcol << 7) + (kq << 3));      \
        const float4 v1 = *(const float4*)(W + (gcol << 7) + (kq << 3) + 4);  \
        *(uint4*)&sh.lin.Ws[(col << 7) + ((kq ^ (col & 7)) << 3)] = pack8(v0, v1); \
      }                                                                       \
    }

    #pragma unroll
    for (int i = 0; i < 4; i++){
      const int cid = i * 64 + l;
      const int row = cid >> 4, kq = cid & 15;
      const size_t gr = (size_t)(r0 + w * 16 + row);
      const float4 v0 = *(const float4*)(x + (gr << 7) + (kq << 3));
      const float4 v1 = *(const float4*)(x + (gr << 7) + (kq << 3) + 4);
      const uint4 o = pack8(v0, v1);
      *(uint4*)&sh.lin.As[w][(row << 7) + ((kq ^ (row & 7)) << 3)] = o;
      *(uint4*)(x16 + (gr << 7) + (kq << 3)) = o;  // 1KB/instr coalesced
    }
    STAGE_W(0)
    __syncthreads();

    const int rloc = l & 15, kg = l >> 4;
    bf8 af[4];
    #pragma unroll
    for (int ks = 0; ks < 4; ks++){
      const int kq = ks * 4 + kg;
      af[ks] = *(const bf8*)&sh.lin.As[w][(rloc << 7) + ((kq ^ (rloc & 7)) << 3)];
    }
    #pragma unroll
    for (int h = 0; h < 2; h++){
      if (h == 1){
        __syncthreads();
        STAGE_W(1)
        __syncthreads();
      }
      #pragma unroll
      for (int c2 = 0; c2 < 4; c2++){
        const int ct = h * 4 + c2;
        f4 acc = {0.f, 0.f, 0.f, 0.f};
        const int col = ct * 16 + rloc;
        const int lcol = c2 * 16 + rloc;          // (col&7)==(lcol&7)
        #pragma unroll
        for (int ks = 0; ks < 4; ks++){
          const int kq = ks * 4 + kg;
          const bf8 bfr = *(const bf8*)&sh.lin.Ws[(lcol << 7) + ((kq ^ (lcol & 7)) << 3)];
          acc = __builtin_amdgcn_mfma_f32_16x16x32_bf16(af[ks], bfr, acc, 0, 0, 0);
        }
        const float bv = bias[col];
        #pragma unroll
        for (int r = 0; r < 4; r++){
          const int row = r0 + w * 16 + kg * 4 + r;
          out[((size_t)row << 7) + col] = (ushort)f2bfbits(acc[r] + bv);
        }
      }
    }
    #undef STAGE_W
  } else if ((int)blockIdx.x < LB + 2 * CH){
    // -------- fixed-slot binning: block owns (dir, chunk of 2048) ----------
    const int sbid = (int)blockIdx.x - LB;       // 0..255
    const int d = sbid >> 7, chunk = sbid & 127;
    const int* __restrict__ e = d ? e_ab : e_ba;
    const int t = threadIdx.x;
    sh.bin.hist[t] = 0; sh.bin.hist[t + 256] = 0;
    __syncthreads();

    int ds[8], ss[8];
    const int base = chunk * 2048;
    #pragma unroll
    for (int k = 0; k < 8; k++){
      const int i = base + k * 256 + t;
      const bool ok = i < E;
      ds[k] = ok ? e[E + i] : -1;
      ss[k] = ok ? e[i] : 0;
      if (ok) atomicAdd(&sh.bin.hist[ds[k] >> 4], 1);   // LDS atomic, 512 bins
    }
    __syncthreads();
    // 512-bin scan: pair-per-thread, wave shfl scans + cross-wave offsets
    const int h0 = sh.bin.hist[2 * t], h1 = sh.bin.hist[2 * t + 1];
    const int pv = h0 + h1;
    {
      int v = pv;
      #pragma unroll
      for (int off = 1; off < 64; off <<= 1){
        const int u = __shfl_up(v, off, 64);
        if ((t & 63) >= off) v += u;
      }
      if ((t & 63) == 63) sh.bin.wtot[t >> 6] = v;
      sh.bin.ex[2 * t] = v;                       // temp: inclusive pair scan
    }
    __syncthreads();
    {
      const int wv = t >> 6;
      int add = 0;
      if (wv > 0) add += sh.bin.wtot[0];
      if (wv > 1) add += sh.bin.wtot[1];
      if (wv > 2) add += sh.bin.wtot[2];
      const int pex = sh.bin.ex[2 * t] + add - pv;   // exclusive start of pair
      sh.bin.ex[2 * t] = pex;      sh.bin.ex[2 * t + 1] = pex + h0;
      sh.bin.cur[2 * t] = pex;     sh.bin.cur[2 * t + 1] = pex + h0;
    }
    __syncthreads();
    #pragma unroll
    for (int k = 0; k < 8; k++){
      if (ds[k] >= 0){
        const int p = atomicAdd(&sh.bin.cur[ds[k] >> 4], 1);   // LDS atomic
        sh.bin.buf[p] = (unsigned)ss[k] | ((unsigned)ds[k] << 13);
      }
    }
    __syncthreads();
    int nv = E - base; nv = nv < 0 ? 0 : (nv > 2048 ? 2048 : nv);
    ccnt[((size_t)d * BK + 2 * t) * CH + chunk]     = (unsigned)min(h0, CAP);
    ccnt[((size_t)d * BK + 2 * t + 1) * CH + chunk] = (unsigned)min(h1, CAP);
    for (int s = t; s < nv; s += 256){
      const unsigned v = sh.bin.buf[s];
      const int bkt = (int)(v >> 17);            // dst>>4
      const int gp = s - sh.bin.ex[bkt];
      if (gp < CAP) scratch[((size_t)(d * BK + bkt) * CH + chunk) * CAP + gp] = v;
    }
  } else {
    if (threadIdx.x == 0) *out0 = 0.0f;
  }
}

// ---- K2: 1024 blk x 256 thr x 16 rows (r13-best: no entry-prefetch; TLP
// beats register-hungry ILP on this latency-bound gather kernel). -----------
__global__ __launch_bounds__(256)
void loss_fused(const ushort* __restrict__ xa, const ushort* __restrict__ xb,
                const ushort* __restrict__ ctx0a, const ushort* __restrict__ ctx0b,
                const unsigned* __restrict__ scratch, const unsigned* __restrict__ ccnt,
                float* __restrict__ out, int n){
  const int nb = n >> 4;                          // 512 jobs per type (16 rows)
  const int jid = xcd_remap((int)blockIdx.x, nb); // XCDs 0-3: type 0, 4-7: type 1
  const int type = jid >= nb;
  const int j16 = jid - (type ? nb : 0);
  const int r0 = j16 << 4;                        // within-type row base
  const ushort* __restrict__ x    = type ? xb : xa;
  const ushort* __restrict__ feat = type ? ctx0a : ctx0b;  // src-side features
  const int t = threadIdx.x, w = t >> 6, l = t & 63;
  const int sg = l >> 4, q = l & 15;

  __shared__ alignas(16) ushort A[16 * 128];      // 4KB
  __shared__ float lpos[16];
  __shared__ float2 part[4][16];
  __shared__ int list[16 * DEG];                  // 4KB
  __shared__ int lcnt[16];
  __shared__ unsigned cc[CH];

  if (t < 16) lcnt[t] = 0;
  const size_t cellbase = (size_t)(type * BK + j16) * CH;  // bucket == j16
  if (t < CH) cc[t] = ccnt[cellbase + t];
  __syncthreads();

  { // phase 0: vec4 scan of OWN bucket only (1x amp, 12KB contiguous)
    for (int i4 = t * 4; i4 < CH * CAP; i4 += 256 * 4){    // 3 iters/thread
      const uint4 v4 = *(const uint4*)(scratch + cellbase * CAP + i4);
      const int cell = i4 / CAP;
      const int s0 = i4 - cell * CAP;
      const int cn = (int)cc[cell];
      #pragma unroll
      for (int j = 0; j < 4; j++){
        if (s0 + j < cn){
          const unsigned v = (&v4.x)[j];
          const int dl = (int)((v >> 13) & 8191u) - r0;    // in [0,16) by construction
          const int p = atomicAdd(&lcnt[dl], 1);
          if (p < DEG) list[dl * DEG + p] = (int)(v & 8191u);
        }
      }
    }
  }
  __syncthreads();

  { // phase 1: gather-mean, row = w*4+sg; 8 loads batched into regs (MLP)
    const int row = w * 4 + sg;
    const int c = min(lcnt[row], DEG);
    const int lb2 = row * DEG;
    int sl0 = list[lb2 + q];
    int sl1 = list[lb2 + 16 + q];
    int sl2 = list[lb2 + 32 + q];
    int sl3 = list[lb2 + 48 + q];

    float a0=0.f,a1=0.f,a2=0.f,a3=0.f,a4=0.f,a5=0.f,a6=0.f,a7=0.f;
    const int lbase = l & 48;
    #define GMEAN_HALF(SL, J, HB)                                              \
    {                                                                          \
      uint4 vv[8]; float wt[8];                                                \
      _Pragma("unroll")                                                        \
      for (int j = 0; j < 8; j++){                                             \
        const int i = (HB) * 8 + j;                                            \
        const int raw = __shfl((SL), lbase | i, 64);                           \
        const bool ok = (J)*16 + i < c;                                        \
        const int src = ok ? raw : 0;                                          \
        wt[j] = ok ? 1.0f : 0.0f;                                              \
        vv[j] = *(const uint4*)(feat + ((size_t)src << 7) + (q << 3));         \
      }                                                                        \
      _Pragma("unroll")                                                        \
      for (int j = 0; j < 8; j++){                                             \
        a0 += wt[j]*bflo(vv[j].x); a1 += wt[j]*bfhi(vv[j].x);                  \
        a2 += wt[j]*bflo(vv[j].y); a3 += wt[j]*bfhi(vv[j].y);                  \
        a4 += wt[j]*bflo(vv[j].z); a5 += wt[j]*bfhi(vv[j].z);                  \
        a6 += wt[j]*bflo(vv[j].w); a7 += wt[j]*bfhi(vv[j].w);                  \
      }                                                                        \
    }
    if (c >  0){ GMEAN_HALF(sl0, 0, 0) GMEAN_HALF(sl0, 0, 1) }
    if (c > 16){ GMEAN_HALF(sl1, 1, 0) GMEAN_HALF(sl1, 1, 1) }
    if (c > 32){ GMEAN_HALF(sl2, 2, 0) GMEAN_HALF(sl2, 2, 1) }
    if (c > 48){ GMEAN_HALF(sl3, 3, 0) GMEAN_HALF(sl3, 3, 1) }
    #undef GMEAN_HALF

    const float inv = 1.0f / (float)(c > 1 ? c : 1);
    uint4 o;
    o.x = f2bfbits(a0*inv) | (f2bfbits(a1*inv) << 16);
    o.y = f2bfbits(a2*inv) | (f2bfbits(a3*inv) << 16);
    o.z = f2bfbits(a4*inv) | (f2bfbits(a5*inv) << 16);
    o.w = f2bfbits(a6*inv) | (f2bfbits(a7*inv) << 16);
    *(uint4*)&A[(row << 7) + ((q ^ (row & 7)) << 3)] = o;
  }
  __syncthreads();

  // phase 2: 2-set software pipeline over this wave's tiles {w, w+4, w+8,
  // w+12, [16 if w==0]} — LSE order identical to r12/r9.
  const int nloc = l & 15, kg = l >> 4;
  const unsigned h = hash_u32((unsigned)jid * 2654435761u + 0x9E3779B9u);
  const unsigned bo = h & 8191u;
  const unsigned aa = (((h >> 13) & 4095u) << 1) | 1u;

  bf8 af[4];
  #pragma unroll
  for (int ks = 0; ks < 4; ks++){
    const int kq = ks * 4 + kg;
    af[ks] = *(const bf8*)&A[(nloc << 7) + ((kq ^ (nloc & 7)) << 3)];
  }

  float M0=-1e30f, M1=-1e30f, M2=-1e30f, M3=-1e30f;
  float S0=0.f, S1=0.f, S2=0.f, S3=0.f;

  int colidA, gA; bool negA; bf8 b0A, b1A, b2A, b3A;
  int colidB, gB; bool negB; bf8 b0B, b1B, b2B, b3B;

  #define LOADSET(S, TILE)                                                     \
  {                                                                            \
    colid##S = (TILE) * 16 + nloc;                                             \
    neg##S = colid##S >= 16;                                                   \
    const int jn_ = colid##S - 16;                                             \
    g##S = neg##S ? (int)((aa * (unsigned)jn_ + bo) & 8191u) : (r0 + colid##S); \
    const ushort* __restrict__ xr_ = x + ((size_t)g##S << 7) + kg * 8;         \
    b0##S = *(const bf8*)(xr_);                                                \
    b1##S = *(const bf8*)(xr_ + 32);                                           \
    b2##S = *(const bf8*)(xr_ + 64);                                           \
    b3##S = *(const bf8*)(xr_ + 96);                                           \
  }

  #define COMPUTESET(S)                                                        \
  {                                                                            \
    f4 acc = {0.f, 0.f, 0.f, 0.f};                                             \
    acc = __builtin_amdgcn_mfma_f32_16x16x32_bf16(af[0], b0##S, acc, 0, 0, 0); \
    acc = __builtin_amdgcn_mfma_f32_16x16x32_bf16(af[1], b1##S, acc, 0, 0, 0); \
    acc = __builtin_amdgcn_mfma_f32_16x16x32_bf16(af[2], b2##S, acc, 0, 0, 0); \
    acc = __builtin_amdgcn_mfma_f32_16x16x32_bf16(af[3], b3##S, acc, 0, 0, 0); \
    const int jn_ = colid##S - 16;                                             \
    _Pragma("unroll")                                                          \
    for (int r = 0; r < 4; r++){                                               \
      const int row_ = kg * 4 + r;                                             \
      const bool valid = neg##S ? (jn_ < 255 && g##S != r0 + row_)             \
                                : (colid##S == row_);                          \
      const float v = acc[r] * 10.0f;                                          \
      if (!neg##S && colid##S == row_) lpos[row_] = v;                         \
      float* Mp; float* Sp;                                                    \
      if (r == 0){ Mp = &M0; Sp = &S0; } else if (r == 1){ Mp = &M1; Sp = &S1; } \
      else if (r == 2){ Mp = &M2; Sp = &S2; } else { Mp = &M3; Sp = &S3; }     \
      if (valid){                                                              \
        const float Mn = fmaxf(*Mp, v);                                        \
        *Sp = *Sp * __expf(*Mp - Mn) + __expf(v - Mn);                         \
        *Mp = Mn;                                                              \
      }                                                                        \
    }                                                                          \
  }

  LOADSET(A, w)
  LOADSET(B, w + 4)
  COMPUTESET(A)                  // tile w
  LOADSET(A, w + 8)
  COMPUTESET(B)                  // tile w+4
  LOADSET(B, w + 12)
  COMPUTESET(A)                  // tile w+8
  if (w == 0){ LOADSET(A, 16) }
  COMPUTESET(B)                  // tile w+12
  if (w == 0){ COMPUTESET(A) }   // tile 16 (negatives 240..254)
  #undef LOADSET
  #undef COMPUTESET

  #define MERGE_LANES(MV, SV)                          \
  {                                                    \
    _Pragma("unroll")                                  \
    for (int o = 1; o < 16; o <<= 1){                  \
      const float Mo = __shfl_xor((MV), o);            \
      const float So = __shfl_xor((SV), o);            \
      const float Mn = fmaxf((MV), Mo);                \
      (SV) = (SV) * __expf((MV) - Mn) + So * __expf(Mo - Mn); \
      (MV) = Mn;                                       \
    }                                                  \
  }
  MERGE_LANES(M0, S0) MERGE_LANES(M1, S1) MERGE_LANES(M2, S2) MERGE_LANES(M3, S3)
  #undef MERGE_LANES

  if (nloc == 0){
    part[w][kg * 4 + 0] = make_float2(M0, S0);
    part[w][kg * 4 + 1] = make_float2(M1, S1);
    part[w][kg * 4 + 2] = make_float2(M2, S2);
    part[w][kg * 4 + 3] = make_float2(M3, S3);
  }
  __syncthreads();

  if (w == 0 && l < 16){
    const int row = l;
    float Mm = -1e30f, Ss = 0.f;
    #pragma unroll
    for (int j = 0; j < 4; j++){
      const float2 ps = part[j][row];
      const float Mn = fmaxf(Mm, ps.x);
      Ss = Ss * __expf(Mm - Mn) + ps.y * __expf(ps.x - Mn);
      Mm = Mn;
    }
    float term = Mm + __logf(Ss) - lpos[row];
    #pragma unroll
    for (int o = 8; o >= 1; o >>= 1) term += __shfl_xor(term, o);
    if (l == 0) atomicAdd(out, term / (logf(256.0f) * (float)(2 * n)));
  }
}

extern "C" void kernel_launch(void* const* d_in, const int* in_sizes, int n_in,
                              void* d_out, int out_size, void* d_ws, size_t ws_size,
                              hipStream_t stream) {
  const float* x_a = (const float*)d_in[0];
  const float* x_b = (const float*)d_in[1];
  const float* W_a = (const float*)d_in[2];
  const float* b_a = (const float*)d_in[3];
  const float* W_b = (const float*)d_in[4];
  const float* b_b = (const float*)d_in[5];
  const int*   e_ab = (const int*)d_in[6];   // [2,E]: [0]=src(a), [1]=dst(b)
  const int*   e_ba = (const int*)d_in[7];   // [0]=src(b), [1]=dst(a)
  const int E = in_sizes[6] / 2;
  const int N = in_sizes[0] / D;             // 8192

  char* p = (char*)d_ws;
  ushort* xa16    = (ushort*)p;   p += (size_t)N * D * 2;
  ushort* xb16    = (ushort*)p;   p += (size_t)N * D * 2;
  ushort* ctx0a   = (ushort*)p;   p += (size_t)N * D * 2;
  ushort* ctx0b   = (ushort*)p;   p += (size_t)N * D * 2;
  unsigned* scratch = (unsigned*)p; p += (size_t)2 * BK * CH * CAP * 4;  // 12.6MB
  unsigned* ccnt  = (unsigned*)p; p += (size_t)2 * BK * CH * 4;          // 512KB

  linear_bin<<<2 * (N / 64) + 2 * CH + 1, 256, 0, stream>>>(
      x_a, x_b, W_a, W_b, b_a, b_b, xa16, xb16, ctx0a, ctx0b,
      e_ba, e_ab, scratch, ccnt, (float*)d_out, E, N);

  loss_fused<<<2 * (N / 16), 256, 0, stream>>>(
      xa16, xb16, ctx0a, ctx0b, scratch, ccnt, (float*)d_out, N);
}